// Round 5
// baseline (30.275 us; speedup 1.0000x reference)
//
#include <hip/hip_runtime.h>
#include <hip/hip_bf16.h>

#define NUM_SAMPLES 256
#define CH 64
#define IMG_H 512
#define IMG_W 512
#define BATCH 8
#define NBLOCKS (BATCH * NUM_SAMPLES)   // 2048

__device__ __forceinline__ float wave_reduce_sum(float v) {
    v += __shfl_xor(v, 32, 64);
    v += __shfl_xor(v, 16, 64);
    v += __shfl_xor(v, 8, 64);
    v += __shfl_xor(v, 4, 64);
    v += __shfl_xor(v, 2, 64);
    v += __shfl_xor(v, 1, 64);
    return v;
}

// Load 3 consecutive floats starting at element index e, using two 8B-aligned
// float2 loads. Window [e&~1, (e&~1)+4) always covers [e, e+3) and never
// crosses the 512-float row end for wi <= 509. Select mask (e&1) is
// wave-uniform (same sample for all lanes).
__device__ __forceinline__ void load_trio(const float* __restrict__ src,
                                          size_t e, float t[3]) {
    const size_t ea = e & ~(size_t)1;
    const int o = (int)(e & 1);
    const float2 A = *(const float2*)(src + ea);
    const float2 B = *(const float2*)(src + ea + 2);
    t[0] = o ? A.y : A.x;
    t[1] = o ? B.x : A.y;
    t[2] = o ? B.y : B.x;
}

// One block of 4 waves per (b, s). wid = (tensor<<1) | rowgroup:
//   rg0: rows 0,1  (4x float2)  -> neighbors (0,0)(0,1)(0,2)(1,0)(1,2), owns ctr
//   rg1: row 2     (2x float2 + ctr dword) -> neighbors (2,0)(2,1)(2,2)
// Lane = channel. k-waves publish normalized vectors via LDS.
__global__ void __launch_bounds__(256)
sample_diff_kernel(const float* __restrict__ fq,
                   const float* __restrict__ fk,
                   const int* __restrict__ ids,
                   float* __restrict__ partial) {
    const int c   = threadIdx.x & 63;   // channel
    const int wid = threadIdx.x >> 6;   // 0..3
    const int rg  = wid & 1;            // 0: rows 0-1, 1: row 2
    const int tk  = wid >> 1;           // 0 = q, 1 = k
    const int bs  = blockIdx.x;
    const int b   = bs >> 8;
    const int s   = bs & (NUM_SAMPLES - 1);

    const int hi = ids[2 * s + 0];
    const int wi = ids[2 * s + 1];

    const float* __restrict__ src = tk ? fk : fq;
    const size_t chbase = (size_t)(b * CH + c) * ((size_t)IMG_H * IMG_W);
    const size_t rowoff = (size_t)hi * IMG_W + wi;

    __shared__ float kx[8][64];   // [neighbor][lane] — 2-way bank alias (free)
    __shared__ float sm[2];

    float nv0, nv1, nv2, nv3, nv4;   // normalized diffs (rg0 uses 5, rg1 uses 3)

    if (rg == 0) {
        float t0[3], t1[3];
        load_trio(src, chbase + rowoff, t0);                 // row 0
        load_trio(src, chbase + rowoff + IMG_W, t1);         // row 1
        const float ctr = t1[1];
        const float d0 = t0[0] - ctr, d1 = t0[1] - ctr, d2 = t0[2] - ctr;
        const float d3 = t1[0] - ctr, d4 = t1[2] - ctr;
        nv0 = d0 * (1.0f / (sqrtf(wave_reduce_sum(d0 * d0)) + 1e-7f));
        nv1 = d1 * (1.0f / (sqrtf(wave_reduce_sum(d1 * d1)) + 1e-7f));
        nv2 = d2 * (1.0f / (sqrtf(wave_reduce_sum(d2 * d2)) + 1e-7f));
        nv3 = d3 * (1.0f / (sqrtf(wave_reduce_sum(d3 * d3)) + 1e-7f));
        nv4 = d4 * (1.0f / (sqrtf(wave_reduce_sum(d4 * d4)) + 1e-7f));
        if (tk == 1) {
            kx[0][c] = nv0; kx[1][c] = nv1; kx[2][c] = nv2;
            kx[3][c] = nv3; kx[4][c] = nv4;
        }
    } else {
        float t2[3];
        load_trio(src, chbase + rowoff + 2 * IMG_W, t2);     // row 2
        const float ctr = src[chbase + rowoff + IMG_W + 1];  // center dword
        const float d0 = t2[0] - ctr, d1 = t2[1] - ctr, d2 = t2[2] - ctr;
        nv0 = d0 * (1.0f / (sqrtf(wave_reduce_sum(d0 * d0)) + 1e-7f));
        nv1 = d1 * (1.0f / (sqrtf(wave_reduce_sum(d1 * d1)) + 1e-7f));
        nv2 = d2 * (1.0f / (sqrtf(wave_reduce_sum(d2 * d2)) + 1e-7f));
        nv3 = 0.0f; nv4 = 0.0f;
        if (tk == 1) {
            kx[5][c] = nv0; kx[6][c] = nv1; kx[7][c] = nv2;
        }
    }
    __syncthreads();

    if (tk == 0) {
        float acc;
        if (rg == 0) {
            acc = fabsf(nv0 - kx[0][c]) + fabsf(nv1 - kx[1][c]) +
                  fabsf(nv2 - kx[2][c]) + fabsf(nv3 - kx[3][c]) +
                  fabsf(nv4 - kx[4][c]);
        } else {
            acc = fabsf(nv0 - kx[5][c]) + fabsf(nv1 - kx[6][c]) +
                  fabsf(nv2 - kx[7][c]);
        }
        acc = wave_reduce_sum(acc);
        if (c == 0) sm[rg] = acc;
    }
    __syncthreads();
    if (threadIdx.x == 0) partial[bs] = sm[0] + sm[1];
}

__global__ void __launch_bounds__(256)
final_reduce_kernel(const float* __restrict__ partial, float* __restrict__ out) {
    __shared__ float sm[4];
    const int t = threadIdx.x;
    // 2048 floats, 8 per lane via two float4 loads (d_ws is 16B-aligned)
    const float4 v0 = ((const float4*)partial)[t * 2 + 0];
    const float4 v1 = ((const float4*)partial)[t * 2 + 1];
    float v = v0.x + v0.y + v0.z + v0.w + v1.x + v1.y + v1.z + v1.w;
    v = wave_reduce_sum(v);
    if ((t & 63) == 0) sm[t >> 6] = v;
    __syncthreads();
    if (t == 0) {
        const float tot = sm[0] + sm[1] + sm[2] + sm[3];
        // mean over B * C * NUM_SAMPLES * 8 = 1048576 elements
        out[0] = tot * (1.0f / 1048576.0f);
    }
}

extern "C" void kernel_launch(void* const* d_in, const int* in_sizes, int n_in,
                              void* d_out, int out_size, void* d_ws, size_t ws_size,
                              hipStream_t stream) {
    const float* fq  = (const float*)d_in[0];
    const float* fk  = (const float*)d_in[1];
    const int*   ids = (const int*)d_in[2];
    float* out     = (float*)d_out;
    float* partial = (float*)d_ws;   // 2048 * 4 = 8 KB

    sample_diff_kernel<<<NBLOCKS, 256, 0, stream>>>(fq, fk, ids, partial);
    final_reduce_kernel<<<1, 256, 0, stream>>>(partial, out);
}